// Round 1
// baseline (846.739 us; speedup 1.0000x reference)
//
#include <hip/hip_runtime.h>
#include <cstddef>

// AdaBP LDPC decoder, MI355X (gfx950).
// Structure: N=4096 vars x 3 edges (contiguous col segments), M=2048 checks x 6
// edges (scattered; inverse list built per-launch). T=30 iterations, 2 kernels
// per iteration. State (2 x E x B f32 = 12.6 MB) lives in d_ws, L2/LLC-resident.

namespace {
constexpr int N  = 4096;
constexpr int M  = 2048;
constexpr int CD = 3;
constexpr int RD = 6;
constexpr int E  = N * CD;     // 12288
constexpr int B  = 128;
constexpr int T  = 30;
constexpr float CLIP    = 15.0f;
constexpr float FEPS    = 1e-6f;
constexpr float MIN_ABS = 6.1180465e-07f;  // -log(tanh(15/2))

// ---- Eng = sum over N of chn^2, per batch column (mean applied later) ----
__global__ __launch_bounds__(128) void k_eng(const float* __restrict__ chn,
                                             float* __restrict__ eng) {
  int b  = threadIdx.x;          // batch column; consecutive threads coalesce
  int v0 = blockIdx.x * 32;
  float s = 0.f;
#pragma unroll
  for (int i = 0; i < 32; ++i) {
    float x = chn[(size_t)(v0 + i) * B + b];
    s += x * x;
  }
  atomicAdd(&eng[b], s);
}

// ---- build check -> edge inverse list (each check has exactly RD edges) ----
__global__ __launch_bounds__(256) void k_build(const int* __restrict__ row_idx,
                                               int* __restrict__ cnt,
                                               int* __restrict__ rlist) {
  int e = blockIdx.x * 256 + threadIdx.x;
  if (e < E) {
    int m    = row_idx[e];
    int slot = atomicAdd(&cnt[m], 1);
    rlist[m * RD + slot] = e;
  }
}

// ---- tiny 1-20-1 MLP with sigmoid output ----
__device__ __forceinline__ float mlp20(float x, const float* __restrict__ W1,
                                       const float* __restrict__ b1,
                                       const float* __restrict__ W2,
                                       const float* __restrict__ b2) {
  float acc = b2[0];
#pragma unroll
  for (int j = 0; j < 20; ++j) {
    float h = fmaxf(x * W1[j] + b1[j], 0.f);
    acc += W2[j] * h;
  }
  return 1.f / (1.f + expf(-acc));
}

__global__ __launch_bounds__(128) void k_mlp(
    const float* __restrict__ eng,
    const float* gW1, const float* gb1, const float* gW2, const float* gb2,
    const float* iW1, const float* ib1, const float* iW2, const float* ib2,
    const float* eW1, const float* eb1, const float* eW2, const float* eb2,
    float* __restrict__ gamma, float* __restrict__ wi, float* __restrict__ we) {
  int b = threadIdx.x;  // 128 threads, one per batch column
  float Eng = eng[b] * (1.f / (float)N);
  // snr = 10*log10(Eng / (1+sqrt(1+Eng)) / (4*RATE)), RATE=0.5
  float snr = 10.f * log10f(Eng / (1.f + sqrtf(1.f + Eng)) * 0.5f);
  gamma[b] = mlp20(snr, gW1, gb1, gW2, gb2);
  wi[b]    = mlp20(snr, iW1, ib1, iW2, ib2);  // MAX_WEIGHT = 1
  we[b]    = mlp20(snr, eW1, eb1, eW2, eb2);
}

// ---- variable-centric phase: col-LOO sums (3 contiguous edges), V2C update.
// Also writes out[t-1] = ell + full col sum (fused: same col sum needed). ----
template <bool WRITE_OUT, bool UPDATE>
__global__ __launch_bounds__(256) void k_var(
    float* __restrict__ v2c, const float* __restrict__ c2v,
    const float* __restrict__ chn, const float* __restrict__ gamma,
    const float* __restrict__ wi, const float* __restrict__ we,
    float* __restrict__ out_prev) {
  int t = threadIdx.x;
  int b = t & (B - 1);
  int v = blockIdx.x * 2 + (t >> 7);
  float web = we[b];
  size_t base = (size_t)v * CD * B + b;
  float w0 = web * c2v[base];
  float w1 = web * c2v[base + B];
  float w2 = web * c2v[base + 2 * B];
  float s   = w0 + w1 + w2;
  float ell = wi[b] * chn[(size_t)v * B + b];
  if (WRITE_OUT) out_prev[(size_t)v * B + b] = ell + s;
  if (UPDATE) {
    float g   = gamma[b];
    float omg = 1.f - g;
    float m0 = v2c[base];
    float m1 = v2c[base + B];
    float m2 = v2c[base + 2 * B];
    v2c[base]         = omg * m0 + g * (ell + s - w0);
    v2c[base + B]     = omg * m1 + g * (ell + s - w1);
    v2c[base + 2 * B] = omg * m2 + g * (ell + s - w2);
  }
}

// ---- check-centric phase: row-LOO parity + log-tanh sums, C2V update ----
__global__ __launch_bounds__(256) void k_chk(const float* __restrict__ v2c,
                                             float* __restrict__ c2v,
                                             const int* __restrict__ rlist,
                                             const float* __restrict__ gamma) {
  int t = threadIdx.x;
  int b = t & (B - 1);
  int m = blockIdx.x * 2 + (t >> 7);
  float g   = gamma[b];
  float omg = 1.f - g;
  int e[RD];
#pragma unroll
  for (int k = 0; k < RD; ++k) e[k] = rlist[m * RD + k];
  float nb[RD], lt[RD];
  float nbs = 0.f, lts = 0.f;
#pragma unroll
  for (int k = 0; k < RD; ++k) {
    float x = v2c[(size_t)e[k] * B + b];
    float l = fminf(fmaxf(x, -CLIP), CLIP);
    float nbk = (l < 0.f) ? 1.f : 0.f;
    float al = fmaxf(fabsf(l), MIN_ABS);
    // lt = log(tanh(al/2)); two-regime numerically-stable form
    float lte;
    if (al > 0.5f) {
      float Ex = expf(-al);
      lte = log1pf(-Ex) - log1pf(Ex);
    } else {
      float em = expm1f(-al);         // -al..0, accurate for small al
      lte = logf(-em) - logf(2.f + em);
    }
    nb[k] = nbk;
    lt[k] = lte;
    nbs += nbk;
    lts += lte;
  }
#pragma unroll
  for (int k = 0; k < RD; ++k) {
    int   cnt = (int)(nbs - nb[k] + 0.5f);  // exact small integer
    float amp = lts - lt[k];                 // <= -5*MIN_ABS < 0
    // c_new = sgn * 2*atanh(exp(amp)*(1-eps)); stable via expm1:
    //   1+x = 2 + expm1(amp) - eps*e^amp ;  1-x = eps*e^amp - expm1(amp)
    float ea  = expf(amp);
    float em1 = expm1f(amp);
    float num = 2.f + em1 - FEPS * ea;
    float den = FEPS * ea - em1;
    float cnew = logf(num / den);
    if (cnt & 1) cnew = -cnew;
    size_t idx = (size_t)e[k] * B + b;
    c2v[idx] = omg * c2v[idx] + g * cnew;
  }
}

}  // namespace

extern "C" void kernel_launch(void* const* d_in, const int* in_sizes, int n_in,
                              void* d_out, int out_size, void* d_ws,
                              size_t ws_size, hipStream_t stream) {
  const float* chn = (const float*)d_in[0];
  const float* gW1 = (const float*)d_in[1];
  const float* gb1 = (const float*)d_in[2];
  const float* gW2 = (const float*)d_in[3];
  const float* gb2 = (const float*)d_in[4];
  const float* iW1 = (const float*)d_in[5];
  const float* ib1 = (const float*)d_in[6];
  const float* iW2 = (const float*)d_in[7];
  const float* ib2 = (const float*)d_in[8];
  const float* eW1 = (const float*)d_in[9];
  const float* eb1 = (const float*)d_in[10];
  const float* eW2 = (const float*)d_in[11];
  const float* eb2 = (const float*)d_in[12];
  const int* row_idx = (const int*)d_in[13];
  // d_in[14] (col_idx) is repeat(arange(N),3) by construction -> implicit.
  float* out = (float*)d_out;

  // workspace layout (float offsets)
  float* ws    = (float*)d_ws;
  float* eng   = ws;                   // 128
  int*   cnt   = (int*)(ws + 128);     // 2048
  float* gamma = ws + 2176;            // 128
  float* wi    = ws + 2304;            // 128
  float* we    = ws + 2432;            // 128
  int*   rlist = (int*)(ws + 2560);    // 12288
  float* v2c   = ws + 16384;           // E*B
  float* c2v   = v2c + (size_t)E * B;  // E*B

  hipMemsetAsync(ws, 0, 2176 * sizeof(float), stream);             // eng + cnt
  hipMemsetAsync(v2c, 0, 2 * (size_t)E * B * sizeof(float), stream);

  k_eng<<<128, 128, 0, stream>>>(chn, eng);
  k_build<<<(E + 255) / 256, 256, 0, stream>>>(row_idx, cnt, rlist);
  k_mlp<<<1, 128, 0, stream>>>(eng, gW1, gb1, gW2, gb2, iW1, ib1, iW2, ib2,
                               eW1, eb1, eW2, eb2, gamma, wi, we);

  for (int t = 0; t < T; ++t) {
    if (t == 0)
      k_var<false, true><<<N / 2, 256, 0, stream>>>(v2c, c2v, chn, gamma, wi,
                                                    we, nullptr);
    else
      k_var<true, true><<<N / 2, 256, 0, stream>>>(
          v2c, c2v, chn, gamma, wi, we, out + (size_t)(t - 1) * N * B);
    k_chk<<<M / 2, 256, 0, stream>>>(v2c, c2v, rlist, gamma);
  }
  // final output row: out[T-1] = ell + col sum of We*msg_C2V (no update)
  k_var<true, false><<<N / 2, 256, 0, stream>>>(
      v2c, c2v, chn, gamma, wi, we, out + (size_t)(T - 1) * N * B);
}